// Round 2
// baseline (182.714 us; speedup 1.0000x reference)
//
#include <hip/hip_runtime.h>
#include <hip/hip_bf16.h>
#include <cmath>

#define NN 4096    // H*W
typedef __attribute__((ext_vector_type(8))) short short8;
typedef __attribute__((ext_vector_type(4))) float f32x4;

__device__ __forceinline__ float bf2f(unsigned short u) {
  union { unsigned int i; float f; } c; c.i = ((unsigned int)u) << 16; return c.f;
}

// ---------------------------------------------------------------------------
// weight prep, coalesced reads (c contiguous per k-row), scattered bf16 writes
//   wcatT[c][k] c<256: qkv_w[k][512+c]; c<320: off_w[k][c-256];
//               c<352: attw_w[k][c-320]; else 0
//   pjT[c][k] = proj_w[k][c]
// ---------------------------------------------------------------------------
__global__ __launch_bounds__(256) void cvt_w(
    const float* __restrict__ qkv_w, const float* __restrict__ off_w,
    const float* __restrict__ attw_w, const float* __restrict__ proj_w,
    __hip_bfloat16* __restrict__ wcatT, __hip_bfloat16* __restrict__ pjT)
{
  const int t = threadIdx.x;
  if (blockIdx.x < 256) {
    int k = blockIdx.x;
    wcatT[t * 256 + k] = __float2bfloat16(qkv_w[k * 768 + 512 + t]);
    if (t < 128) {
      int c2 = 256 + t;
      float v = 0.f;
      if (c2 < 320)      v = off_w[k * 64 + (c2 - 256)];
      else if (c2 < 352) v = attw_w[k * 32 + (c2 - 320)];
      wcatT[c2 * 256 + k] = __float2bfloat16(v);
    }
  } else {
    int k = blockIdx.x - 256;
    pjT[t * 256 + k] = __float2bfloat16(proj_w[k * 256 + t]);
  }
}

// ---------------------------------------------------------------------------
// fused v-GEMM + offset/attention logits + sampling-table epilogue.
// RETILED: 256 threads (4 waves, 1x4), tile 64 rows x 384 cols, grid 512 ->
// LDS 35.8 KB -> 2 independent blocks/CU (was 1) so barrier drains overlap
// with the co-resident block. XCD-chunked swizzle: block chunk k (64 tiles)
// = batch k stays on XCD k, so vb/table it produces stay in the local L2 for
// the consumer kernel (same swizzle there).
// ---------------------------------------------------------------------------
__global__ __launch_bounds__(256) void gemm_voff(
    const float* __restrict__ x,
    const __hip_bfloat16* __restrict__ wcatT,
    const float* __restrict__ vbias,
    const float* __restrict__ off_b, const float* __restrict__ attw_b,
    __hip_bfloat16* __restrict__ vb,
    unsigned int* __restrict__ table)
{
  __shared__ float smemf[8960];               // 35840 B
  short* As = (short*)smemf;                  // 64 * 40 shorts = 5120 B
  short* Bs = As + 64 * 40;                   // 384 * 40 shorts = 30720 B
  float (*L)[100] = (float(*)[100])smemf;     // 64*100*4 = 25600 B, aliased AFTER K loop

  const int t = threadIdx.x;
  const int bid = blockIdx.x;
  // 512 blocks = 8 XCD chunks x 64 tiles; chunk k == batch k
  const int m0 = (((bid & 7) << 6) | (bid >> 3)) * 64;
  const int wave = t >> 6, lane = t & 63, q = lane >> 4, ln = lane & 15;
  const int wn = wave * 96;

  f32x4 acc[4][6] = {};

  const int arow = t >> 2, aseg = t & 3;          // A staging: 64 rows x 4 segs
  const float* apg = x + (size_t)(m0 + arow) * 256 + aseg * 8;

  for (int k0 = 0; k0 < 256; k0 += 32) {
    // A: 64x32 fp32 -> bf16
    float4 f0 = *(const float4*)(apg + k0);
    float4 f1 = *(const float4*)(apg + k0 + 4);
    alignas(16) __hip_bfloat16 cv[8] = {
      __float2bfloat16(f0.x), __float2bfloat16(f0.y), __float2bfloat16(f0.z), __float2bfloat16(f0.w),
      __float2bfloat16(f1.x), __float2bfloat16(f1.y), __float2bfloat16(f1.z), __float2bfloat16(f1.w)};
    *(int4*)&As[arow * 40 + aseg * 8] = *(int4*)cv;
    // B: 384x32 bf16, 1536 16B units / 256 thr = 6 each
#pragma unroll
    for (int i = 0; i < 6; ++i) {
      int u = t + i * 256;
      int brow = u >> 2, bseg = u & 3;
      *(int4*)&Bs[brow * 40 + bseg * 8] =
          *(const int4*)&wcatT[(size_t)brow * 256 + k0 + bseg * 8];
    }
    __syncthreads();
    short8 a[4], b[6];
#pragma unroll
    for (int i = 0; i < 4; ++i) a[i] = *(const short8*)&As[(i * 16 + ln) * 40 + q * 8];
#pragma unroll
    for (int j = 0; j < 6; ++j) b[j] = *(const short8*)&Bs[(wn + j * 16 + ln) * 40 + q * 8];
#pragma unroll
    for (int i = 0; i < 4; ++i)
#pragma unroll
      for (int j = 0; j < 6; ++j)
        acc[i][j] = __builtin_amdgcn_mfma_f32_16x16x32_bf16(a[i], b[j], acc[i][j], 0, 0, 0);
    __syncthreads();
  }

  // v outputs + logits to LDS
#pragma unroll
  for (int j = 0; j < 6; ++j) {
    int col = wn + j * 16 + ln;
    if (col < 256) {
      float bv = vbias[col];
#pragma unroll
      for (int i = 0; i < 4; ++i) {
        int rowb = m0 + i * 16 + q * 4;
#pragma unroll
        for (int r = 0; r < 4; ++r)
          vb[(size_t)(rowb + r) * 256 + col] = __float2bfloat16(acc[i][j][r] + bv);
      }
    } else if (col < 352) {
      int lc = col - 256;
      float bv = (lc < 64) ? off_b[lc] : attw_b[lc - 64];
#pragma unroll
      for (int i = 0; i < 4; ++i)
#pragma unroll
        for (int r = 0; r < 4; ++r)
          L[i * 16 + q * 4 + r][lc] = acc[i][j][r] + bv;
    }
  }
  __syncthreads();

  // table epilogue: 512 (row,head) pairs, 2 per thread
#pragma unroll
  for (int it = 0; it < 2; ++it) {
    int pl = t + it * 256;
    int rr = pl >> 3, h = pl & 7;
    int row = m0 + rr;
    int nl = row & (NN - 1);
    float refx = (float)(nl & 63);
    float refy = (float)(nl >> 6);

    float a0 = L[rr][64 + h * 4 + 0], a1 = L[rr][64 + h * 4 + 1];
    float a2 = L[rr][64 + h * 4 + 2], a3 = L[rr][64 + h * 4 + 3];
    float mx = fmaxf(fmaxf(a0, a1), fmaxf(a2, a3));
    float e0 = expf(a0 - mx), e1 = expf(a1 - mx), e2 = expf(a2 - mx), e3 = expf(a3 - mx);
    float inv = 1.f / (e0 + e1 + e2 + e3);
    float at[4] = {e0 * inv, e1 * inv, e2 * inv, e3 * inv};

    alignas(16) unsigned short idxs[16];
    alignas(16) _Float16 wsv[16];
#pragma unroll
    for (int p = 0; p < 4; ++p) {
      float gx = refx + 2.f * tanhf(L[rr][h * 8 + p * 2 + 0]);
      float gy = refy + 2.f * tanhf(L[rr][h * 8 + p * 2 + 1]);
      float x0f = floorf(gx), y0f = floorf(gy);
      int x0 = (int)x0f, y0 = (int)y0f;
      int x1 = x0 + 1,   y1 = y0 + 1;
      float wx1 = gx - x0f, wx0 = 1.f - wx1;
      float wy1 = gy - y0f, wy0 = 1.f - wy1;
      int cx0 = min(max(x0, 0), 63), cx1 = min(max(x1, 0), 63);
      int cy0 = min(max(y0, 0), 63), cy1 = min(max(y1, 0), 63);
      float vx0 = (x0 >= 0 && x0 <= 63) ? 1.f : 0.f;
      float vx1 = (x1 >= 0 && x1 <= 63) ? 1.f : 0.f;
      float vy0 = (y0 >= 0 && y0 <= 63) ? 1.f : 0.f;
      float vy1 = (y1 >= 0 && y1 <= 63) ? 1.f : 0.f;
      float ap = at[p];
      idxs[p * 4 + 0] = (unsigned short)(cy0 * 64 + cx0);
      idxs[p * 4 + 1] = (unsigned short)(cy0 * 64 + cx1);
      idxs[p * 4 + 2] = (unsigned short)(cy1 * 64 + cx0);
      idxs[p * 4 + 3] = (unsigned short)(cy1 * 64 + cx1);
      wsv[p * 4 + 0] = (_Float16)(ap * wx0 * wy0 * vx0 * vy0);
      wsv[p * 4 + 1] = (_Float16)(ap * wx1 * wy0 * vx1 * vy0);
      wsv[p * 4 + 2] = (_Float16)(ap * wx0 * wy1 * vx0 * vy1);
      wsv[p * 4 + 3] = (_Float16)(ap * wx1 * wy1 * vx1 * vy1);
    }
    uint4* dst = (uint4*)(table + ((size_t)row * 8 + h) * 16);  // pair-major
    dst[0] = *(uint4*)&idxs[0];
    dst[1] = *(uint4*)&idxs[8];
    dst[2] = *(uint4*)&wsv[0];
    dst[3] = *(uint4*)&wsv[8];
  }
}

// ---------------------------------------------------------------------------
// FUSED sampler + proj GEMM. Block = 64 rows x all 256 out cols, 256 threads.
// Phase 1: sample the 64x256 bf16 A-tile (y rows) directly into LDS.
// Phase 2: proven 16x16x32 MFMA GEMM vs pjT, fp32 out with bias.
// Eliminates the yb global round trip (16.7 MB write + 33.5 MB read) and one
// kernel launch. Same XCD-chunked swizzle as gemm_voff: XCD k gathers only
// batch k's v slice (2 MB) + table slice (2 MB) -> L2-resident.
// ---------------------------------------------------------------------------
__global__ __launch_bounds__(256) void sample_proj(
    const __hip_bfloat16* __restrict__ v,
    const unsigned int* __restrict__ table,
    const short* __restrict__ BT,          // pjT [col][k] bf16-as-short
    const float* __restrict__ bias,
    float* __restrict__ out)
{
  __shared__ short As[64 * 264];           // 33792 B, full-K A tile, +8 pad/row
  __shared__ short Bs[256 * 40];           // 20480 B, per-k-step B tile
  const int t = threadIdx.x;
  const int bid = blockIdx.x;
  const int m0 = (((bid & 7) << 6) | (bid >> 3)) * 64;   // batch k on XCD k

  // ---- phase 1: sample. 64 rows x 8 heads x 4 chan-groups = 2048 tasks ----
#pragma unroll 2
  for (int it = 0; it < 8; ++it) {
    int task = t + it * 256;
    int g = task & 3, pairL = task >> 2;
    int h = pairL & 7, rr = pairL >> 3;
    int row = m0 + rr;
    size_t pg = (size_t)row * 8 + h;
    // 64B table entry -> registers (lanes sharing a pair hit the same L1 lines)
    const uint4* te = (const uint4*)(table + pg * 16);
    alignas(16) uint4 tb[4];
    tb[0] = te[0]; tb[1] = te[1]; tb[2] = te[2]; tb[3] = te[3];
    const unsigned short* ip = (const unsigned short*)tb;
    const _Float16* wp = (const _Float16*)(tb + 2);
    const char* vbase = (const char*)(v + (size_t)(row >> 12) * NN * 256 + h * 32 + g * 8);
    float sacc[8] = {};
#pragma unroll
    for (int j = 0; j < 16; ++j) {
      float w = (float)wp[j];
      int idx = ip[j];
      int4 pk = *(const int4*)(vbase + (size_t)idx * 512);
      const unsigned short* u = (const unsigned short*)&pk;
#pragma unroll
      for (int c = 0; c < 8; ++c) sacc[c] += w * bf2f(u[c]);
    }
    alignas(16) __hip_bfloat16 o[8];
#pragma unroll
    for (int c = 0; c < 8; ++c) o[c] = __float2bfloat16(sacc[c]);
    *(int4*)&As[rr * 264 + h * 32 + g * 8] = *(int4*)o;
  }
  __syncthreads();

  // ---- phase 2: GEMM out[64,256] = As @ BT^T + bias ----
  const int wave = t >> 6, lane = t & 63, q = lane >> 4, ln = lane & 15;
  const int wn = wave * 64;
  f32x4 acc[4][4] = {};

  for (int k0 = 0; k0 < 256; k0 += 32) {
    // B: 256x32 bf16, 1024 16B units / 256 thr = 4 each
#pragma unroll
    for (int u2 = 0; u2 < 4; ++u2) {
      int c = t + u2 * 256;
      int col = c >> 2, kq = c & 3;
      *(int4*)&Bs[col * 40 + kq * 8] =
          *(const int4*)&BT[(size_t)col * 256 + k0 + kq * 8];
    }
    __syncthreads();
    short8 a[4], b[4];
#pragma unroll
    for (int i = 0; i < 4; ++i) a[i] = *(const short8*)&As[(i * 16 + ln) * 264 + k0 + q * 8];
#pragma unroll
    for (int j = 0; j < 4; ++j) b[j] = *(const short8*)&Bs[(wn + j * 16 + ln) * 40 + q * 8];
#pragma unroll
    for (int i = 0; i < 4; ++i)
#pragma unroll
      for (int j = 0; j < 4; ++j)
        acc[i][j] = __builtin_amdgcn_mfma_f32_16x16x32_bf16(a[i], b[j], acc[i][j], 0, 0, 0);
    __syncthreads();
  }

#pragma unroll
  for (int j = 0; j < 4; ++j) {
    int col = wn + j * 16 + ln;
    float bv = bias[col];
#pragma unroll
    for (int i = 0; i < 4; ++i) {
      int rowb = m0 + i * 16 + q * 4;
#pragma unroll
      for (int r = 0; r < 4; ++r)
        out[(size_t)(rowb + r) * 256 + col] = acc[i][j][r] + bv;
    }
  }
}

// ---------------------------------------------------------------------------
extern "C" void kernel_launch(void* const* d_in, const int* in_sizes, int n_in,
                              void* d_out, int out_size, void* d_ws, size_t ws_size,
                              hipStream_t stream) {
  const float* x      = (const float*)d_in[0];
  const float* qkv_w  = (const float*)d_in[1];
  const float* qkv_b  = (const float*)d_in[2];
  const float* off_w  = (const float*)d_in[3];
  const float* off_b  = (const float*)d_in[4];
  const float* attw_w = (const float*)d_in[5];
  const float* attw_b = (const float*)d_in[6];
  const float* proj_w = (const float*)d_in[7];
  const float* proj_b = (const float*)d_in[8];
  float* out = (float*)d_out;

  char* ws = (char*)d_ws;
  __hip_bfloat16* vb    = (__hip_bfloat16*)(ws);                 // 16 MiB
  unsigned int*   table = (unsigned int*)  (ws + 16777216);      // 16 MiB
  __hip_bfloat16* wcatT = (__hip_bfloat16*)(ws + 33554432);      // 192 KiB
  __hip_bfloat16* pjT   = (__hip_bfloat16*)(ws + 33751040);      // 128 KiB

  cvt_w<<<512, 256, 0, stream>>>(qkv_w, off_w, attw_w, proj_w, wcatT, pjT);
  gemm_voff<<<512, 256, 0, stream>>>(x, wcatT, qkv_b + 512, off_b, attw_b, vb, table);
  sample_proj<<<512, 256, 0, stream>>>(vb, table, (const short*)pjT, proj_b, out);
}

// Round 5
// 148.070 us; speedup vs baseline: 1.2340x; 1.2340x over previous
//
#include <hip/hip_runtime.h>
#include <hip/hip_bf16.h>
#include <cmath>

#define NN 4096    // H*W
typedef __attribute__((ext_vector_type(8))) short short8;
typedef __attribute__((ext_vector_type(4))) float f32x4;

__device__ __forceinline__ float bf2f(unsigned short u) {
  union { unsigned int i; float f; } c; c.i = ((unsigned int)u) << 16; return c.f;
}

// ---------------------------------------------------------------------------
// weight prep, coalesced reads (c contiguous per k-row), scattered bf16 writes
//   wcatT[c][k] c<256: qkv_w[k][512+c]; c<320: off_w[k][c-256];
//               c<352: attw_w[k][c-320]; else 0
//   pjT[c][k] = proj_w[k][c]
// ---------------------------------------------------------------------------
__global__ __launch_bounds__(256) void cvt_w(
    const float* __restrict__ qkv_w, const float* __restrict__ off_w,
    const float* __restrict__ attw_w, const float* __restrict__ proj_w,
    __hip_bfloat16* __restrict__ wcatT, __hip_bfloat16* __restrict__ pjT)
{
  const int t = threadIdx.x;
  if (blockIdx.x < 256) {
    int k = blockIdx.x;
    wcatT[t * 256 + k] = __float2bfloat16(qkv_w[k * 768 + 512 + t]);
    if (t < 128) {
      int c2 = 256 + t;
      float v = 0.f;
      if (c2 < 320)      v = off_w[k * 64 + (c2 - 256)];
      else if (c2 < 352) v = attw_w[k * 32 + (c2 - 320)];
      wcatT[c2 * 256 + k] = __float2bfloat16(v);
    }
  } else {
    int k = blockIdx.x - 256;
    pjT[t * 256 + k] = __float2bfloat16(proj_w[k * 256 + t]);
  }
}

// ---------------------------------------------------------------------------
// fused v-GEMM + offset/attention logits + sampling-table epilogue.
// ROUND-0 PROVEN SHAPE: 512 threads (8 waves, 2x4), tile 128 rows x 384 cols,
// grid 256, x read exactly once. ONLY change vs round-0: XCD-chunked blockIdx
// swizzle so chunk k (32 tiles = batch k) runs on XCD k and its vb/table
// output stays in that XCD's L2 for the downstream sampler.
// ---------------------------------------------------------------------------
__global__ __launch_bounds__(512) void gemm_voff(
    const float* __restrict__ x,
    const __hip_bfloat16* __restrict__ wcatT,
    const float* __restrict__ vbias,
    const float* __restrict__ off_b, const float* __restrict__ attw_b,
    __hip_bfloat16* __restrict__ vb,
    unsigned int* __restrict__ table)
{
  __shared__ float smemf[12800];              // 51200 B
  short* As = (short*)smemf;                  // 128 * 40 shorts = 10240 B
  short* Bs = As + 128 * 40;                  // 384 * 40 shorts = 30720 B
  float (*L)[100] = (float(*)[100])smemf;     // aliased AFTER the K loop

  const int t = threadIdx.x;
  const int bid = blockIdx.x;
  // 256 blocks = 8 XCD chunks x 32 tiles; chunk k == batch k
  const int m0 = (((bid & 7) << 5) | (bid >> 3)) * 128;
  const int wave = t >> 6, lane = t & 63, q = lane >> 4, ln = lane & 15;
  const int wm = (wave & 1) * 64, wn = (wave >> 1) * 96;

  f32x4 acc[4][6] = {};

  const int arow = t >> 2, aseg = t & 3;          // A staging: 128 rows x 4 segs
  const float* apg = x + (size_t)(m0 + arow) * 256 + aseg * 8;

  for (int k0 = 0; k0 < 256; k0 += 32) {
    // A: 128x32 fp32 -> bf16
    float4 f0 = *(const float4*)(apg + k0);
    float4 f1 = *(const float4*)(apg + k0 + 4);
    alignas(16) __hip_bfloat16 cv[8] = {
      __float2bfloat16(f0.x), __float2bfloat16(f0.y), __float2bfloat16(f0.z), __float2bfloat16(f0.w),
      __float2bfloat16(f1.x), __float2bfloat16(f1.y), __float2bfloat16(f1.z), __float2bfloat16(f1.w)};
    *(int4*)&As[arow * 40 + aseg * 8] = *(int4*)cv;
    // B: 384x32 bf16, 1536 16B units / 512 thr = 3 each
#pragma unroll
    for (int i = 0; i < 3; ++i) {
      int u = t + i * 512;
      int brow = u >> 2, bseg = u & 3;
      *(int4*)&Bs[brow * 40 + bseg * 8] =
          *(const int4*)&wcatT[(size_t)brow * 256 + k0 + bseg * 8];
    }
    __syncthreads();
    short8 a[4], b[6];
#pragma unroll
    for (int i = 0; i < 4; ++i) a[i] = *(const short8*)&As[(wm + i * 16 + ln) * 40 + q * 8];
#pragma unroll
    for (int j = 0; j < 6; ++j) b[j] = *(const short8*)&Bs[(wn + j * 16 + ln) * 40 + q * 8];
#pragma unroll
    for (int i = 0; i < 4; ++i)
#pragma unroll
      for (int j = 0; j < 6; ++j)
        acc[i][j] = __builtin_amdgcn_mfma_f32_16x16x32_bf16(a[i], b[j], acc[i][j], 0, 0, 0);
    __syncthreads();
  }

  // v outputs + logits to LDS
#pragma unroll
  for (int j = 0; j < 6; ++j) {
    int col = wn + j * 16 + ln;
    if (col < 256) {
      float bv = vbias[col];
#pragma unroll
      for (int i = 0; i < 4; ++i) {
        int rowb = m0 + wm + i * 16 + q * 4;
#pragma unroll
        for (int r = 0; r < 4; ++r)
          vb[(size_t)(rowb + r) * 256 + col] = __float2bfloat16(acc[i][j][r] + bv);
      }
    } else if (col < 352) {
      int lc = col - 256;
      float bv = (lc < 64) ? off_b[lc] : attw_b[lc - 64];
#pragma unroll
      for (int i = 0; i < 4; ++i)
#pragma unroll
        for (int r = 0; r < 4; ++r)
          L[wm + i * 16 + q * 4 + r][lc] = acc[i][j][r] + bv;
    }
  }
  __syncthreads();

  // table epilogue: 1024 (row,head) pairs, 2 per thread
#pragma unroll
  for (int it = 0; it < 2; ++it) {
    int pl = t + it * 512;
    int rr = pl >> 3, h = pl & 7;
    int row = m0 + rr;
    int nl = row & (NN - 1);
    float refx = (float)(nl & 63);
    float refy = (float)(nl >> 6);

    float a0 = L[rr][64 + h * 4 + 0], a1 = L[rr][64 + h * 4 + 1];
    float a2 = L[rr][64 + h * 4 + 2], a3 = L[rr][64 + h * 4 + 3];
    float mx = fmaxf(fmaxf(a0, a1), fmaxf(a2, a3));
    float e0 = expf(a0 - mx), e1 = expf(a1 - mx), e2 = expf(a2 - mx), e3 = expf(a3 - mx);
    float inv = 1.f / (e0 + e1 + e2 + e3);
    float at[4] = {e0 * inv, e1 * inv, e2 * inv, e3 * inv};

    alignas(16) unsigned short idxs[16];
    alignas(16) _Float16 wsv[16];
#pragma unroll
    for (int p = 0; p < 4; ++p) {
      float gx = refx + 2.f * tanhf(L[rr][h * 8 + p * 2 + 0]);
      float gy = refy + 2.f * tanhf(L[rr][h * 8 + p * 2 + 1]);
      float x0f = floorf(gx), y0f = floorf(gy);
      int x0 = (int)x0f, y0 = (int)y0f;
      int x1 = x0 + 1,   y1 = y0 + 1;
      float wx1 = gx - x0f, wx0 = 1.f - wx1;
      float wy1 = gy - y0f, wy0 = 1.f - wy1;
      int cx0 = min(max(x0, 0), 63), cx1 = min(max(x1, 0), 63);
      int cy0 = min(max(y0, 0), 63), cy1 = min(max(y1, 0), 63);
      float vx0 = (x0 >= 0 && x0 <= 63) ? 1.f : 0.f;
      float vx1 = (x1 >= 0 && x1 <= 63) ? 1.f : 0.f;
      float vy0 = (y0 >= 0 && y0 <= 63) ? 1.f : 0.f;
      float vy1 = (y1 >= 0 && y1 <= 63) ? 1.f : 0.f;
      float ap = at[p];
      idxs[p * 4 + 0] = (unsigned short)(cy0 * 64 + cx0);
      idxs[p * 4 + 1] = (unsigned short)(cy0 * 64 + cx1);
      idxs[p * 4 + 2] = (unsigned short)(cy1 * 64 + cx0);
      idxs[p * 4 + 3] = (unsigned short)(cy1 * 64 + cx1);
      wsv[p * 4 + 0] = (_Float16)(ap * wx0 * wy0 * vx0 * vy0);
      wsv[p * 4 + 1] = (_Float16)(ap * wx1 * wy0 * vx1 * vy0);
      wsv[p * 4 + 2] = (_Float16)(ap * wx0 * wy1 * vx0 * vy1);
      wsv[p * 4 + 3] = (_Float16)(ap * wx1 * wy1 * vx1 * vy1);
    }
    uint4* dst = (uint4*)(table + ((size_t)row * 8 + h) * 16);  // pair-major (R2)
    dst[0] = *(uint4*)&idxs[0];
    dst[1] = *(uint4*)&idxs[8];
    dst[2] = *(uint4*)&wsv[0];
    dst[3] = *(uint4*)&wsv[8];
  }
}

// ---------------------------------------------------------------------------
// sampler (R0-proven shape): thread = (pair, 8-channel group). 64 pairs/block,
// table staged in LDS, gathers are 16B dwordx4 from v. y written bf16.
// ONLY change vs round-0: XCD-chunked swizzle — 4096 blocks = 8 chunks x 512;
// chunk k == batch k, whose v slice (2 MB) + table slice (2 MB) sit in XCD
// k's L2 (written there by gemm_voff with the matching swizzle).
// ---------------------------------------------------------------------------
__global__ __launch_bounds__(256) void sample_kernel(
    const __hip_bfloat16* __restrict__ v,
    const unsigned int* __restrict__ table,
    __hip_bfloat16* __restrict__ y)
{
  __shared__ uint4 Tab[256];                 // 64 pairs x 64 B
  const int t = threadIdx.x;
  const int bid = blockIdx.x;
  const int p0 = (((bid & 7) << 9) | (bid >> 3)) * 64;   // batch k on XCD k
  Tab[t] = *(const uint4*)(table + (size_t)p0 * 16 + t * 4);
  __syncthreads();

  const int g = t & 3, p = t >> 2;
  const int pg = p0 + p;
  const int h = pg & 7;
  const int row = pg >> 3;                   // [0, 32768)
  const int b = row >> 12;
  const unsigned short* ip = (const unsigned short*)&Tab[p * 4];
  const _Float16* wp = (const _Float16*)((const char*)&Tab[p * 4] + 32);
  const char* vbase = (const char*)(v + (size_t)b * NN * 256 + h * 32 + g * 8);

  float acc[8] = {};
#pragma unroll
  for (int j = 0; j < 16; ++j) {
    float w = (float)wp[j];
    int idx = ip[j];
    int4 pk = *(const int4*)(vbase + (size_t)idx * 512);
    const unsigned short* u = (const unsigned short*)&pk;
#pragma unroll
    for (int c = 0; c < 8; ++c) acc[c] += w * bf2f(u[c]);
  }
  alignas(16) __hip_bfloat16 o[8];
#pragma unroll
  for (int c = 0; c < 8; ++c) o[c] = __float2bfloat16(acc[c]);
  *(int4*)((char*)y + ((size_t)row * 256 + h * 32 + g * 8) * 2) = *(int4*)o;
}

// ---------------------------------------------------------------------------
// proj GEMM (R0-proven): out[M,256] = yb @ pjT^T + proj_b, fp32 out.
// ONLY change vs round-0: 1D grid 512 with XCD-chunked decomposition so the
// m-tiles of batch k (yb slice in XCD k's L2) run on XCD k.
// ---------------------------------------------------------------------------
__global__ __launch_bounds__(256) void gemm_proj(
    const short* __restrict__ A, const short* __restrict__ BT,
    const float* __restrict__ bias, float* __restrict__ out)
{
  __shared__ short As[128 * 40];
  __shared__ short Bs[128 * 40];
  const int t = threadIdx.x;
  const int bid = blockIdx.x;
  // 512 blocks = 8 chunks x 64; chunk k: 32 m-tiles (batch k) x 2 n-tiles
  const int local = bid >> 3;
  const int n0 = (local & 1) * 128;
  const int m0 = (((bid & 7) << 5) | (local >> 1)) * 128;
  const int wave = t >> 6, lane = t & 63, q = lane >> 4, ln = lane & 15;
  const int wm = (wave & 1) * 64, wn = (wave >> 1) * 64;

  f32x4 acc[4][4] = {};

  for (int k0 = 0; k0 < 256; k0 += 32) {
#pragma unroll
    for (int u = 0; u < 2; ++u) {
      int c = t + u * 256;
      int row = c >> 2, kq = c & 3;
      *(int4*)&As[row * 40 + kq * 8] =
          *(const int4*)&A[(size_t)(m0 + row) * 256 + k0 + kq * 8];
      *(int4*)&Bs[row * 40 + kq * 8] =
          *(const int4*)&BT[(size_t)(n0 + row) * 256 + k0 + kq * 8];
    }
    __syncthreads();
    short8 a[4], b[4];
#pragma unroll
    for (int i = 0; i < 4; ++i) a[i] = *(const short8*)&As[(wm + i * 16 + ln) * 40 + q * 8];
#pragma unroll
    for (int j = 0; j < 4; ++j) b[j] = *(const short8*)&Bs[(wn + j * 16 + ln) * 40 + q * 8];
#pragma unroll
    for (int i = 0; i < 4; ++i)
#pragma unroll
      for (int j = 0; j < 4; ++j)
        acc[i][j] = __builtin_amdgcn_mfma_f32_16x16x32_bf16(a[i], b[j], acc[i][j], 0, 0, 0);
    __syncthreads();
  }

#pragma unroll
  for (int j = 0; j < 4; ++j) {
    int col = n0 + wn + j * 16 + ln;
    float bv = bias[col];
#pragma unroll
    for (int i = 0; i < 4; ++i) {
      int rowb = m0 + wm + i * 16 + q * 4;
#pragma unroll
      for (int r = 0; r < 4; ++r)
        out[(size_t)(rowb + r) * 256 + col] = acc[i][j][r] + bv;
    }
  }
}

// ---------------------------------------------------------------------------
extern "C" void kernel_launch(void* const* d_in, const int* in_sizes, int n_in,
                              void* d_out, int out_size, void* d_ws, size_t ws_size,
                              hipStream_t stream) {
  const float* x      = (const float*)d_in[0];
  const float* qkv_w  = (const float*)d_in[1];
  const float* qkv_b  = (const float*)d_in[2];
  const float* off_w  = (const float*)d_in[3];
  const float* off_b  = (const float*)d_in[4];
  const float* attw_w = (const float*)d_in[5];
  const float* attw_b = (const float*)d_in[6];
  const float* proj_w = (const float*)d_in[7];
  const float* proj_b = (const float*)d_in[8];
  float* out = (float*)d_out;

  char* ws = (char*)d_ws;
  __hip_bfloat16* vb    = (__hip_bfloat16*)(ws);                 // 16 MiB
  __hip_bfloat16* yb    = (__hip_bfloat16*)(ws + 16777216);      // 16 MiB
  unsigned int*   table = (unsigned int*)  (ws + 33554432);      // 16 MiB
  __hip_bfloat16* wcatT = (__hip_bfloat16*)(ws + 50331648);      // 192 KiB
  __hip_bfloat16* pjT   = (__hip_bfloat16*)(ws + 50528256);      // 128 KiB

  cvt_w<<<512, 256, 0, stream>>>(qkv_w, off_w, attw_w, proj_w, wcatT, pjT);
  gemm_voff<<<256, 512, 0, stream>>>(x, wcatT, qkv_b + 512, off_b, attw_b, vb, table);
  sample_kernel<<<4096, 256, 0, stream>>>(vb, table, yb);
  gemm_proj<<<512, 256, 0, stream>>>((const short*)yb, (const short*)pjT, proj_b, out);
}

// Round 7
// 142.477 us; speedup vs baseline: 1.2824x; 1.0393x over previous
//
#include <hip/hip_runtime.h>
#include <hip/hip_bf16.h>
#include <cmath>

#define NN 4096    // H*W
typedef __attribute__((ext_vector_type(8))) short short8;
typedef __attribute__((ext_vector_type(4))) float f32x4;

__device__ __forceinline__ float bf2f(unsigned short u) {
  union { unsigned int i; float f; } c; c.i = ((unsigned int)u) << 16; return c.f;
}

// ---------------------------------------------------------------------------
// weight prep, coalesced reads (c contiguous per k-row), scattered bf16 writes
//   wcatT[c][k] c<256: qkv_w[k][512+c]; c<320: off_w[k][c-256];
//               c<352: attw_w[k][c-320]; else 0
//   pjT[c][k] = proj_w[k][c]
// ---------------------------------------------------------------------------
__global__ __launch_bounds__(256) void cvt_w(
    const float* __restrict__ qkv_w, const float* __restrict__ off_w,
    const float* __restrict__ attw_w, const float* __restrict__ proj_w,
    __hip_bfloat16* __restrict__ wcatT, __hip_bfloat16* __restrict__ pjT)
{
  const int t = threadIdx.x;
  if (blockIdx.x < 256) {
    int k = blockIdx.x;
    wcatT[t * 256 + k] = __float2bfloat16(qkv_w[k * 768 + 512 + t]);
    if (t < 128) {
      int c2 = 256 + t;
      float v = 0.f;
      if (c2 < 320)      v = off_w[k * 64 + (c2 - 256)];
      else if (c2 < 352) v = attw_w[k * 32 + (c2 - 320)];
      wcatT[c2 * 256 + k] = __float2bfloat16(v);
    }
  } else {
    int k = blockIdx.x - 256;
    pjT[t * 256 + k] = __float2bfloat16(proj_w[k * 256 + t]);
  }
}

// ---------------------------------------------------------------------------
// fused v-GEMM + offset/attention logits + COMPACT sampling-table epilogue.
// R5-proven shape: 512 threads (8 waves, 2x4), tile 128 rows x 384 cols,
// grid 256, XCD-chunked swizzle (chunk k == batch k on XCD k).
// NEW vs R5: table entry is 32 B/pair (8 fp16 dx,dy + 4 fp16 attn + pad)
// instead of 64 B of precomputed corners — halves table traffic; corner
// math moves to the sampler.
// ---------------------------------------------------------------------------
__global__ __launch_bounds__(512) void gemm_voff(
    const float* __restrict__ x,
    const __hip_bfloat16* __restrict__ wcatT,
    const float* __restrict__ vbias,
    const float* __restrict__ off_b, const float* __restrict__ attw_b,
    __hip_bfloat16* __restrict__ vb,
    unsigned int* __restrict__ table)
{
  __shared__ float smemf[12800];              // 51200 B
  short* As = (short*)smemf;                  // 128 * 40 shorts = 10240 B
  short* Bs = As + 128 * 40;                  // 384 * 40 shorts = 30720 B
  float (*L)[100] = (float(*)[100])smemf;     // aliased AFTER the K loop

  const int t = threadIdx.x;
  const int bid = blockIdx.x;
  // 256 blocks = 8 XCD chunks x 32 tiles; chunk k == batch k
  const int m0 = (((bid & 7) << 5) | (bid >> 3)) * 128;
  const int wave = t >> 6, lane = t & 63, q = lane >> 4, ln = lane & 15;
  const int wm = (wave & 1) * 64, wn = (wave >> 1) * 96;

  f32x4 acc[4][6] = {};

  const int arow = t >> 2, aseg = t & 3;          // A staging: 128 rows x 4 segs
  const float* apg = x + (size_t)(m0 + arow) * 256 + aseg * 8;

  for (int k0 = 0; k0 < 256; k0 += 32) {
    // A: 128x32 fp32 -> bf16
    float4 f0 = *(const float4*)(apg + k0);
    float4 f1 = *(const float4*)(apg + k0 + 4);
    alignas(16) __hip_bfloat16 cv[8] = {
      __float2bfloat16(f0.x), __float2bfloat16(f0.y), __float2bfloat16(f0.z), __float2bfloat16(f0.w),
      __float2bfloat16(f1.x), __float2bfloat16(f1.y), __float2bfloat16(f1.z), __float2bfloat16(f1.w)};
    *(int4*)&As[arow * 40 + aseg * 8] = *(int4*)cv;
    // B: 384x32 bf16, 1536 16B units / 512 thr = 3 each
#pragma unroll
    for (int i = 0; i < 3; ++i) {
      int u = t + i * 512;
      int brow = u >> 2, bseg = u & 3;
      *(int4*)&Bs[brow * 40 + bseg * 8] =
          *(const int4*)&wcatT[(size_t)brow * 256 + k0 + bseg * 8];
    }
    __syncthreads();
    short8 a[4], b[6];
#pragma unroll
    for (int i = 0; i < 4; ++i) a[i] = *(const short8*)&As[(wm + i * 16 + ln) * 40 + q * 8];
#pragma unroll
    for (int j = 0; j < 6; ++j) b[j] = *(const short8*)&Bs[(wn + j * 16 + ln) * 40 + q * 8];
#pragma unroll
    for (int i = 0; i < 4; ++i)
#pragma unroll
      for (int j = 0; j < 6; ++j)
        acc[i][j] = __builtin_amdgcn_mfma_f32_16x16x32_bf16(a[i], b[j], acc[i][j], 0, 0, 0);
    __syncthreads();
  }

  // v outputs + logits to LDS
#pragma unroll
  for (int j = 0; j < 6; ++j) {
    int col = wn + j * 16 + ln;
    if (col < 256) {
      float bv = vbias[col];
#pragma unroll
      for (int i = 0; i < 4; ++i) {
        int rowb = m0 + wm + i * 16 + q * 4;
#pragma unroll
        for (int r = 0; r < 4; ++r)
          vb[(size_t)(rowb + r) * 256 + col] = __float2bfloat16(acc[i][j][r] + bv);
      }
    } else if (col < 352) {
      int lc = col - 256;
      float bv = (lc < 64) ? off_b[lc] : attw_b[lc - 64];
#pragma unroll
      for (int i = 0; i < 4; ++i)
#pragma unroll
        for (int r = 0; r < 4; ++r)
          L[wm + i * 16 + q * 4 + r][lc] = acc[i][j][r] + bv;
    }
  }
  __syncthreads();

  // compact table epilogue: 1024 (row,head) pairs, 2 per thread, 24 B each
#pragma unroll
  for (int it = 0; it < 2; ++it) {
    int pl = t + it * 512;
    int rr = pl >> 3, h = pl & 7;
    int row = m0 + rr;

    float a0 = L[rr][64 + h * 4 + 0], a1 = L[rr][64 + h * 4 + 1];
    float a2 = L[rr][64 + h * 4 + 2], a3 = L[rr][64 + h * 4 + 3];
    float mx = fmaxf(fmaxf(a0, a1), fmaxf(a2, a3));
    float e0 = expf(a0 - mx), e1 = expf(a1 - mx), e2 = expf(a2 - mx), e3 = expf(a3 - mx);
    float inv = 1.f / (e0 + e1 + e2 + e3);

    alignas(16) _Float16 pk[12];
#pragma unroll
    for (int p = 0; p < 4; ++p) {
      pk[p * 2 + 0] = (_Float16)(2.f * tanhf(L[rr][h * 8 + p * 2 + 0]));
      pk[p * 2 + 1] = (_Float16)(2.f * tanhf(L[rr][h * 8 + p * 2 + 1]));
    }
    pk[8]  = (_Float16)(e0 * inv);
    pk[9]  = (_Float16)(e1 * inv);
    pk[10] = (_Float16)(e2 * inv);
    pk[11] = (_Float16)(e3 * inv);

    size_t pg = (size_t)row * 8 + h;
    *(uint4*)(table + pg * 8)     = *(uint4*)&pk[0];   // 16 B: dx,dy x4
    *(uint2*)(table + pg * 8 + 4) = *(uint2*)&pk[8];   //  8 B: attn x4
  }
}

// ---------------------------------------------------------------------------
// sampler: thread = (pair, 8-channel group). 64 pairs/block, compact 32 B
// table entries staged in LDS; corners recomputed in-register (fp16 dx,dy ->
// ~1e-3 px, well under bf16 value noise). Gathers are 16B dwordx4 from v.
// XCD-chunked swizzle as R5: chunk k == batch k, v/table slices in XCD-k L2.
// ---------------------------------------------------------------------------
__global__ __launch_bounds__(256) void sample_kernel(
    const __hip_bfloat16* __restrict__ v,
    const unsigned int* __restrict__ table,
    __hip_bfloat16* __restrict__ y)
{
  __shared__ uint4 Tab[128];                 // 64 pairs x 32 B
  const int t = threadIdx.x;
  const int bid = blockIdx.x;
  const int p0 = (((bid & 7) << 9) | (bid >> 3)) * 64;   // batch k on XCD k
  if (t < 128) Tab[t] = *(const uint4*)(table + (size_t)p0 * 8 + t * 4);
  __syncthreads();

  const int g = t & 3, p = t >> 2;
  const int pg = p0 + p;
  const int h = pg & 7;
  const int row = pg >> 3;                   // [0, 32768)
  const int b = row >> 12;
  const int nl = row & (NN - 1);
  const float refx = (float)(nl & 63);
  const float refy = (float)(nl >> 6);

  const _Float16* dp  = (const _Float16*)&Tab[p * 2];      // dx,dy x4
  const _Float16* ap_ = (const _Float16*)&Tab[p * 2 + 1];  // attn x4

  alignas(16) unsigned short idxs[16];
  float ws[16];
#pragma unroll
  for (int pp = 0; pp < 4; ++pp) {
    float gx = refx + (float)dp[2 * pp + 0];
    float gy = refy + (float)dp[2 * pp + 1];
    float x0f = floorf(gx), y0f = floorf(gy);
    int x0 = (int)x0f, y0 = (int)y0f;
    int x1 = x0 + 1,   y1 = y0 + 1;
    float wx1 = gx - x0f, wx0 = 1.f - wx1;
    float wy1 = gy - y0f, wy0 = 1.f - wy1;
    int cx0 = min(max(x0, 0), 63), cx1 = min(max(x1, 0), 63);
    int cy0 = min(max(y0, 0), 63), cy1 = min(max(y1, 0), 63);
    float vx0 = (x0 >= 0 && x0 <= 63) ? 1.f : 0.f;
    float vx1 = (x1 >= 0 && x1 <= 63) ? 1.f : 0.f;
    float vy0 = (y0 >= 0 && y0 <= 63) ? 1.f : 0.f;
    float vy1 = (y1 >= 0 && y1 <= 63) ? 1.f : 0.f;
    float apv = (float)ap_[pp];
    idxs[pp * 4 + 0] = (unsigned short)(cy0 * 64 + cx0);
    idxs[pp * 4 + 1] = (unsigned short)(cy0 * 64 + cx1);
    idxs[pp * 4 + 2] = (unsigned short)(cy1 * 64 + cx0);
    idxs[pp * 4 + 3] = (unsigned short)(cy1 * 64 + cx1);
    ws[pp * 4 + 0] = apv * wx0 * wy0 * vx0 * vy0;
    ws[pp * 4 + 1] = apv * wx1 * wy0 * vx1 * vy0;
    ws[pp * 4 + 2] = apv * wx0 * wy1 * vx0 * vy1;
    ws[pp * 4 + 3] = apv * wx1 * wy1 * vx1 * vy1;
  }

  const char* vbase = (const char*)(v + (size_t)b * NN * 256 + h * 32 + g * 8);

  float acc[8] = {};
#pragma unroll
  for (int j = 0; j < 16; ++j) {
    float w = ws[j];
    int idx = idxs[j];
    int4 pk = *(const int4*)(vbase + (size_t)idx * 512);
    const unsigned short* u = (const unsigned short*)&pk;
#pragma unroll
    for (int c = 0; c < 8; ++c) acc[c] += w * bf2f(u[c]);
  }
  alignas(16) __hip_bfloat16 o[8];
#pragma unroll
  for (int c = 0; c < 8; ++c) o[c] = __float2bfloat16(acc[c]);
  *(int4*)((char*)y + ((size_t)row * 256 + h * 32 + g * 8) * 2) = *(int4*)o;
}

// ---------------------------------------------------------------------------
// proj GEMM: out[M,256] = yb @ pjT^T + proj_b, fp32 out.
// NEW vs R5: 64x256 tile (all n-cols in one block) so yb is read exactly
// once (was twice). 256 thr, 4 waves x (64x64), grid 512, LDS 25.6 KB ->
// ~4 blocks/CU. XCD-chunked: m-tiles of batch k on XCD k (yb slice L2-local).
// ---------------------------------------------------------------------------
__global__ __launch_bounds__(256) void gemm_proj(
    const short* __restrict__ A, const short* __restrict__ BT,
    const float* __restrict__ bias, float* __restrict__ out)
{
  __shared__ short As[64 * 40];              // 5120 B
  __shared__ short Bs[256 * 40];             // 20480 B
  const int t = threadIdx.x;
  const int bid = blockIdx.x;
  // 512 blocks = 8 chunks x 64 m-tiles; chunk k == batch k
  const int m0 = (((bid & 7) << 6) | (bid >> 3)) * 64;
  const int wave = t >> 6, lane = t & 63, q = lane >> 4, ln = lane & 15;
  const int wn = wave * 64;

  f32x4 acc[4][4] = {};

  const int arow = t >> 2, aseg = t & 3;     // A staging: 64 rows x 4 segs
  const short* apg = A + (size_t)(m0 + arow) * 256 + aseg * 8;

  for (int k0 = 0; k0 < 256; k0 += 32) {
    *(int4*)&As[arow * 40 + aseg * 8] = *(const int4*)(apg + k0);
    // B: 256x32 bf16, 1024 16B units / 256 thr = 4 each
#pragma unroll
    for (int u2 = 0; u2 < 4; ++u2) {
      int c = t + u2 * 256;
      int col = c >> 2, kq = c & 3;
      *(int4*)&Bs[col * 40 + kq * 8] =
          *(const int4*)&BT[(size_t)col * 256 + k0 + kq * 8];
    }
    __syncthreads();
    short8 a[4], b[4];
#pragma unroll
    for (int i = 0; i < 4; ++i) a[i] = *(const short8*)&As[(i * 16 + ln) * 40 + q * 8];
#pragma unroll
    for (int j = 0; j < 4; ++j) b[j] = *(const short8*)&Bs[(wn + j * 16 + ln) * 40 + q * 8];
#pragma unroll
    for (int i = 0; i < 4; ++i)
#pragma unroll
      for (int j = 0; j < 4; ++j)
        acc[i][j] = __builtin_amdgcn_mfma_f32_16x16x32_bf16(a[i], b[j], acc[i][j], 0, 0, 0);
    __syncthreads();
  }

#pragma unroll
  for (int j = 0; j < 4; ++j) {
    int col = wn + j * 16 + ln;
    float bv = bias[col];
#pragma unroll
    for (int i = 0; i < 4; ++i) {
      int rowb = m0 + i * 16 + q * 4;
#pragma unroll
      for (int r = 0; r < 4; ++r)
        out[(size_t)(rowb + r) * 256 + col] = acc[i][j][r] + bv;
    }
  }
}

// ---------------------------------------------------------------------------
extern "C" void kernel_launch(void* const* d_in, const int* in_sizes, int n_in,
                              void* d_out, int out_size, void* d_ws, size_t ws_size,
                              hipStream_t stream) {
  const float* x      = (const float*)d_in[0];
  const float* qkv_w  = (const float*)d_in[1];
  const float* qkv_b  = (const float*)d_in[2];
  const float* off_w  = (const float*)d_in[3];
  const float* off_b  = (const float*)d_in[4];
  const float* attw_w = (const float*)d_in[5];
  const float* attw_b = (const float*)d_in[6];
  const float* proj_w = (const float*)d_in[7];
  const float* proj_b = (const float*)d_in[8];
  float* out = (float*)d_out;

  char* ws = (char*)d_ws;
  __hip_bfloat16* vb    = (__hip_bfloat16*)(ws);                 // 16 MiB
  __hip_bfloat16* yb    = (__hip_bfloat16*)(ws + 16777216);      // 16 MiB
  unsigned int*   table = (unsigned int*)  (ws + 33554432);      // 8 MiB (compact)
  __hip_bfloat16* wcatT = (__hip_bfloat16*)(ws + 41943040);      // 192 KiB
  __hip_bfloat16* pjT   = (__hip_bfloat16*)(ws + 42139648);      // 128 KiB

  cvt_w<<<512, 256, 0, stream>>>(qkv_w, off_w, attw_w, proj_w, wcatT, pjT);
  gemm_voff<<<256, 512, 0, stream>>>(x, wcatT, qkv_b + 512, off_b, attw_b, vb, table);
  sample_kernel<<<4096, 256, 0, stream>>>(vb, table, yb);
  gemm_proj<<<512, 256, 0, stream>>>((const short*)yb, (const short*)pjT, proj_b, out);
}